// Round 8
// baseline (112.537 us; speedup 1.0000x reference)
//
#include <hip/hip_runtime.h>

// TopKActivation: out = relu(x) masked to the row-wise top-k of relu(x).
// [16384 x 4096] fp32, k=64. One 256-thread block per row, interleaved
// coalesced layout (thread t, chunk j -> cols j*1024 + 4t..+3).
//
// LESSON LEDGER:
//  R3: persistent blocks + prefetch + LDS-only barriers -> 214us (lost TLP).
//  R4: launch_bounds(256,8) -> 302us (forced 64-VGPR cap, write amplification).
//  R5: NT stores -> 523MB writes (1.95x ideal), partial-line HBM writes. BAD.
//  R6: plain stores -> 127.5us.
//  R7: coalesced interleaved layout -> 100.9us (was 64B lane stride = 4x
//      transactions; now 16B stride, 1KiB/wave instruction).
//  R8 (this): 4 barriers -> 2, no wave0-only select. Per-wave ballot
//      compaction into private 128-slot segments (no atomics, no count
//      barrier); all 4 waves redundantly run the radix select on private
//      256-bin histograms (wave-internal, no barrier, no idle waves).
//
// Select: candidates > 1.5f (~274/row on N(0,1)); 4x8-bit MSB radix on float
// bits (positive floats order as uints). Exact full-block fallback if any
// segment >128 or cnt<k. Ties at T resolved stably (lowest column first) to
// match XLA top_k via packed 4x16-bit block scan.

constexpr int ROW_LEN = 4096;
constexpr int TPB     = 256;
constexpr int SEG     = 128;   // per-wave candidate capacity
constexpr int CAP     = 512;   // 4 * SEG
constexpr unsigned int KPRE_BITS = 0x3FC00000u; // bits of 1.5f

typedef float f32x4 __attribute__((ext_vector_type(4)));

__global__ __launch_bounds__(TPB, 4)
void topk_relu_kernel(const float* __restrict__ x, const int* __restrict__ kptr,
                      float* __restrict__ out, int rows)
{
    __shared__ alignas(16) int hist4[4][256];   // per-wave histograms
    __shared__ unsigned int cand[CAP];          // 4 segments of 128
    __shared__ int scnt[4];
    __shared__ unsigned long long wtot64[4];
    __shared__ int sel_digit, sel_kk, sel_flag;

    const int row = blockIdx.x;
    if (row >= rows) return;
    const int tid  = threadIdx.x;
    const int lane = tid & 63;
    const int wid  = tid >> 6;

    int k = *kptr;
    if (k > ROW_LEN) k = ROW_LEN;

    // ---- load row, interleaved coalesced ----
    const float* __restrict__ xrow = x + (size_t)row * ROW_LEN;
    unsigned int key[16];
#pragma unroll
    for (int j = 0; j < 4; ++j) {
        f32x4 v = *(const f32x4*)(xrow + j * 1024 + tid * 4);
#pragma unroll
        for (int c = 0; c < 4; ++c)
            key[4 * j + c] = __float_as_uint(fmaxf(v[c], 0.0f));
    }

    // ---- per-wave ballot compaction of candidates > 1.5f into own segment ----
    int base = 0;
#pragma unroll
    for (int j = 0; j < 16; ++j) {
        const bool p = key[j] > KPRE_BITS;
        const unsigned long long mask = __ballot(p);
        const int prior = __builtin_amdgcn_mbcnt_hi(
            (unsigned int)(mask >> 32),
            __builtin_amdgcn_mbcnt_lo((unsigned int)mask, 0));
        const int idx = base + prior;
        if (p && idx < SEG) cand[(wid << 7) + idx] = key[j];
        base += (int)__popcll(mask);
    }
    if (lane == 0) scnt[wid] = base;
    __syncthreads(); // B1: segments + counts ready

    const int c0 = scnt[0], c1 = scnt[1], c2 = scnt[2], c3 = scnt[3];
    const int cnt = c0 + c1 + c2 + c3;
    const bool segok = (c0 <= SEG) & (c1 <= SEG) & (c2 <= SEG) & (c3 <= SEG);

    unsigned int T;
    int need;

    if (cnt >= k && segok) { // cnt <= CAP implied by segok
        // ---- redundant select: every wave computes T on its own histogram ----
        const int sc[4] = {c0, c1, c2, c3};
        unsigned int c[8];
#pragma unroll
        for (int i = 0; i < 8; ++i) {
            const int s   = i >> 1;                 // segment (compile-time)
            const int off = lane + 64 * (i & 1);
            c[i] = (off < sc[s]) ? cand[(s << 7) + off] : 0u;
        }
        int* __restrict__ myhist = &hist4[wid][0];
        int kk = k;
        unsigned int prefix = 0;
#pragma unroll
        for (int p = 0; p < 4; ++p) {
            const int shift = 24 - 8 * p;
            ((int4*)myhist)[lane] = make_int4(0, 0, 0, 0);
#pragma unroll
            for (int i = 0; i < 8; ++i) {
                const unsigned int ci = c[i];
                if (ci != 0u && (p == 0 || (ci >> (shift + 8)) == prefix))
                    atomicAdd(&myhist[(ci >> shift) & 255u], 1);
            }
            const int4 h = ((const int4*)myhist)[lane];
            const int h0 = h.x, h1 = h.y, h2 = h.z, h3 = h.w;
            const int lsum = h0 + h1 + h2 + h3;
            int suf = lsum; // inclusive suffix sum across lanes
#pragma unroll
            for (int d = 1; d < 64; d <<= 1) {
                int v = __shfl_down(suf, d);
                if (lane < 64 - d) suf += v;
            }
            const unsigned long long mm = __ballot(suf >= kk); // nonzero: cnt>=kk
            const int L = 63 - __clzll(mm);
            int dig = 0, kkn = 0;
            if (lane == L) {
                int cum = suf - lsum;
                const int hh[4] = {h0, h1, h2, h3};
#pragma unroll
                for (int b = 3; b >= 0; --b) {
                    if (cum + hh[b] >= kk) { dig = lane * 4 + b; kkn = kk - cum; break; }
                    cum += hh[b];
                }
            }
            dig = __shfl(dig, L);
            kk  = __shfl(kkn, L);
            prefix = (prefix << 8) | (unsigned int)dig;
        }
        T = prefix;
        need = kk;
    } else {
        // ---- exact fallback: full-block 4-pass histogram over all positives ----
        int* __restrict__ hist = &hist4[0][0];
        int kk = k;
        unsigned int prefix = 0;
        int t0 = 0;
        for (int p = 0; p < 4; ++p) {
            const int shift = 24 - 8 * p;
            hist[tid] = 0;
            if (tid == 0) sel_flag = 0;
            __syncthreads();
#pragma unroll
            for (int j = 0; j < 16; ++j) {
                const unsigned int kj = key[j];
                if (kj != 0u && (p == 0 || (kj >> (shift + 8)) == prefix))
                    atomicAdd(&hist[(kj >> shift) & 255u], 1);
            }
            __syncthreads();
            if (tid < 64) {
                const int b0 = tid * 4;
                const int h0 = hist[b0 + 0], h1 = hist[b0 + 1];
                const int h2 = hist[b0 + 2], h3 = hist[b0 + 3];
                const int lsum = h0 + h1 + h2 + h3;
                int suf = lsum;
#pragma unroll
                for (int d = 1; d < 64; d <<= 1) {
                    int v = __shfl_down(suf, d);
                    if (lane < 64 - d) suf += v;
                }
                const unsigned long long mm = __ballot(suf >= kk);
                if (mm == 0ull) {
                    if (lane == 0) sel_flag = 1;
                } else {
                    const int L = 63 - __clzll(mm);
                    if (lane == L) {
                        int cum = suf - lsum;
                        const int hh[4] = {h0, h1, h2, h3};
#pragma unroll
                        for (int b = 3; b >= 0; --b) {
                            if (cum + hh[b] >= kk) { sel_digit = b0 + b; sel_kk = kk - cum; break; }
                            cum += hh[b];
                        }
                    }
                }
            }
            __syncthreads();
            if (sel_flag) { t0 = 1; break; }
            prefix = (prefix << 8) | (unsigned int)sel_digit;
            kk = sel_kk;
            __syncthreads(); // protect sel_* from next pass's re-init
        }
        if (t0) { T = 0u; need = 0; }
        else    { T = prefix; need = kk; }
    }

    // ---- stable rank of ==T elements in column order ----
    // Column order == lexicographic (j, tid, c). Packed 4x16-bit eq-counts,
    // one block scan gives per-group prefixes and group totals (<=4096/lane).
    unsigned long long packed = 0ull;
#pragma unroll
    for (int j = 0; j < 4; ++j) {
        int e = 0;
#pragma unroll
        for (int c = 0; c < 4; ++c) e += (key[4 * j + c] == T) ? 1 : 0;
        packed |= (unsigned long long)e << (16 * j);
    }
    unsigned long long incp = packed;
#pragma unroll
    for (int d = 1; d < 64; d <<= 1) {
        unsigned long long v = __shfl_up(incp, d);
        if (lane >= d) incp += v;
    }
    if (lane == 63) wtot64[wid] = incp;
    __syncthreads(); // B2
    unsigned long long b64 = 0ull;
    for (int w = 0; w < wid; ++w) b64 += wtot64[w];
    const unsigned long long exclp = b64 + incp - packed;
    const unsigned long long tot = wtot64[0] + wtot64[1] + wtot64[2] + wtot64[3];
    int S[4];
    S[0] = 0;
    S[1] = (int)(tot & 0xFFFFull);
    S[2] = S[1] + (int)((tot >> 16) & 0xFFFFull);
    S[3] = S[2] + (int)((tot >> 32) & 0xFFFFull);

    // ---- emit, coalesced, plain stores ----
    float* __restrict__ orow = out + (size_t)row * ROW_LEN;
#pragma unroll
    for (int j = 0; j < 4; ++j) {
        int rr = S[j] + (int)((exclp >> (16 * j)) & 0xFFFFull);
        f32x4 v;
#pragma unroll
        for (int c2 = 0; c2 < 4; ++c2) {
            const unsigned int kj = key[4 * j + c2];
            const bool eq = (kj == T);
            const bool keep = (kj > T) || (eq && rr < need);
            v[c2] = keep ? __uint_as_float(kj) : 0.0f;
            rr += eq ? 1 : 0;
        }
        *(f32x4*)(orow + j * 1024 + tid * 4) = v;
    }
}

extern "C" void kernel_launch(void* const* d_in, const int* in_sizes, int n_in,
                              void* d_out, int out_size, void* d_ws, size_t ws_size,
                              hipStream_t stream)
{
    const float* x    = (const float*)d_in[0];
    const int*   kptr = (const int*)d_in[1];
    float*       out  = (float*)d_out;
    const int rows = in_sizes[0] / ROW_LEN;
    topk_relu_kernel<<<rows, TPB, 0, stream>>>(x, kptr, out, rows);
}

// Round 9
// 100.058 us; speedup vs baseline: 1.1247x; 1.1247x over previous
//
#include <hip/hip_runtime.h>

// TopKActivation: out = relu(x) masked to the row-wise top-k of relu(x).
// [16384 x 4096] fp32, k=64. One 256-thread block per row, interleaved
// coalesced layout (thread t, chunk j -> cols j*1024 + 4t..+3).
//
// LESSON LEDGER:
//  R3: persistent blocks + prefetch + LDS-only barriers -> 214us (lost TLP).
//  R4: launch_bounds(256,8) -> 302us (write amplification).
//  R5: NT stores -> 523MB writes (1.95x ideal): partial-line HBM writes. BAD.
//  R6: plain stores -> 127.5us.
//  R7: coalesced interleaved layout -> 100.9us (was 64B lane stride = 4x txns).
//  R8: redundant all-wave select -> 112.5us. 4x LDS hist traffic on shared
//      pipes swamped the removed idle-wave time. Wave0 select is fine.
//  R9 (this): R7 + ballot compaction (no atomics, no init barrier; 4->3
//      barriers) + tie fast-path (skip stable-rank scan & per-element rank
//      bookkeeping unless a tie at T is ambiguous — ~0.6 rows per 16384).
//
// Select: candidates > 1.5f (~274/row on N(0,1)) ballot-compacted into 4
// per-wave 128-slot LDS segments; wave 0 runs 4x8-bit MSB radix on float bits
// (positive floats order as uints). Exact full-block fallback if any segment
// overflows or cnt < k. Ties at T stable (lowest column first) == XLA top_k.

constexpr int ROW_LEN = 4096;
constexpr int TPB     = 256;
constexpr int SEG     = 128;   // per-wave candidate capacity
constexpr unsigned int KPRE_BITS = 0x3FC00000u; // bits of 1.5f

typedef float f32x4 __attribute__((ext_vector_type(4)));

__global__ __launch_bounds__(TPB, 4)
void topk_relu_kernel(const float* __restrict__ x, const int* __restrict__ kptr,
                      float* __restrict__ out, int rows)
{
    __shared__ alignas(16) int hist[256];
    __shared__ unsigned int cand[4 * SEG];  // 4 segments of 128
    __shared__ int scnt[4];
    __shared__ unsigned int selT;
    __shared__ int selNeed;
    __shared__ int wtot[4];
    __shared__ unsigned long long wtot64[4];
    __shared__ int sel_digit, sel_kk, sel_flag;

    const int row = blockIdx.x;
    if (row >= rows) return;
    const int tid  = threadIdx.x;
    const int lane = tid & 63;
    const int wid  = tid >> 6;

    int k = *kptr;
    if (k > ROW_LEN) k = ROW_LEN;

    // ---- load row, interleaved coalesced: thread t chunk j -> cols j*1024+4t..+3 ----
    const float* __restrict__ xrow = x + (size_t)row * ROW_LEN;
    unsigned int key[16];
#pragma unroll
    for (int j = 0; j < 4; ++j) {
        f32x4 v = *(const f32x4*)(xrow + j * 1024 + tid * 4);
#pragma unroll
        for (int c = 0; c < 4; ++c)
            key[4 * j + c] = __float_as_uint(fmaxf(v[c], 0.0f));
    }

    // ---- per-wave ballot compaction of candidates > 1.5f (no atomics) ----
    int base = 0;
#pragma unroll
    for (int j = 0; j < 16; ++j) {
        const bool p = key[j] > KPRE_BITS;
        const unsigned long long mask = __ballot(p);
        const int prior = __builtin_amdgcn_mbcnt_hi(
            (unsigned int)(mask >> 32),
            __builtin_amdgcn_mbcnt_lo((unsigned int)mask, 0));
        const int idx = base + prior;
        if (p && idx < SEG) cand[(wid << 7) + idx] = key[j];
        base += (int)__popcll(mask);
    }
    if (lane == 0) scnt[wid] = base;
    __syncthreads(); // B1: segments + counts ready

    const int c0 = scnt[0], c1 = scnt[1], c2 = scnt[2], c3 = scnt[3];
    const int cnt = c0 + c1 + c2 + c3;
    const bool segok = (c0 <= SEG) & (c1 <= SEG) & (c2 <= SEG) & (c3 <= SEG);

    unsigned int T;
    int need;

    if (cnt >= k && segok) {
        // ---- fast select: wave 0 only ----
        if (wid == 0) {
            const int sc[4] = {c0, c1, c2, c3};
            unsigned int c[8];
#pragma unroll
            for (int i = 0; i < 8; ++i) {
                const int s   = i >> 1;
                const int off = lane + 64 * (i & 1);
                c[i] = (off < sc[s]) ? cand[(s << 7) + off] : 0u;
            }
            int kk = k;
            unsigned int prefix = 0;
#pragma unroll
            for (int p = 0; p < 4; ++p) {
                const int shift = 24 - 8 * p;
                ((int4*)hist)[lane] = make_int4(0, 0, 0, 0);
#pragma unroll
                for (int i = 0; i < 8; ++i) {
                    const unsigned int ci = c[i];
                    if (ci != 0u && (p == 0 || (ci >> (shift + 8)) == prefix))
                        atomicAdd(&hist[(ci >> shift) & 255u], 1);
                }
                const int4 h = ((const int4*)hist)[lane];
                const int h0 = h.x, h1 = h.y, h2 = h.z, h3 = h.w;
                const int lsum = h0 + h1 + h2 + h3;
                int suf = lsum; // inclusive suffix sum across lanes
#pragma unroll
                for (int d = 1; d < 64; d <<= 1) {
                    int v = __shfl_down(suf, d);
                    if (lane < 64 - d) suf += v;
                }
                const unsigned long long mm = __ballot(suf >= kk); // nonzero: cnt>=kk
                const int L = 63 - __clzll(mm);
                int dig = 0, kkn = 0;
                if (lane == L) {
                    int cum = suf - lsum;
                    const int hh[4] = {h0, h1, h2, h3};
#pragma unroll
                    for (int b = 3; b >= 0; --b) {
                        if (cum + hh[b] >= kk) { dig = lane * 4 + b; kkn = kk - cum; break; }
                        cum += hh[b];
                    }
                }
                dig = __shfl(dig, L);
                kk  = __shfl(kkn, L);
                prefix = (prefix << 8) | (unsigned int)dig;
            }
            if (lane == 0) { selT = prefix; selNeed = kk; }
        }

        // ---- meanwhile every wave computes its eq/gt counts (pre-T not possible;
        //      this is cheap post-barrier work) ----
        __syncthreads(); // B2: T ready
        T = selT;
        need = selNeed;
    } else {
        // ---- exact fallback: full-block 4-pass histogram over all positives ----
        int kk = k;
        unsigned int prefix = 0;
        int t0 = 0;
        for (int p = 0; p < 4; ++p) {
            const int shift = 24 - 8 * p;
            hist[tid & 255] = 0;
            if (tid == 0) sel_flag = 0;
            __syncthreads();
#pragma unroll
            for (int j = 0; j < 16; ++j) {
                const unsigned int kj = key[j];
                if (kj != 0u && (p == 0 || (kj >> (shift + 8)) == prefix))
                    atomicAdd(&hist[(kj >> shift) & 255u], 1);
            }
            __syncthreads();
            if (tid < 64) {
                const int b0 = tid * 4;
                const int h0 = hist[b0 + 0], h1 = hist[b0 + 1];
                const int h2 = hist[b0 + 2], h3 = hist[b0 + 3];
                const int lsum = h0 + h1 + h2 + h3;
                int suf = lsum;
#pragma unroll
                for (int d = 1; d < 64; d <<= 1) {
                    int v = __shfl_down(suf, d);
                    if (lane < 64 - d) suf += v;
                }
                const unsigned long long mm = __ballot(suf >= kk);
                if (mm == 0ull) {
                    if (lane == 0) sel_flag = 1;
                } else {
                    const int L = 63 - __clzll(mm);
                    if (lane == L) {
                        int cum = suf - lsum;
                        const int hh[4] = {h0, h1, h2, h3};
#pragma unroll
                        for (int b = 3; b >= 0; --b) {
                            if (cum + hh[b] >= kk) { sel_digit = b0 + b; sel_kk = kk - cum; break; }
                            cum += hh[b];
                        }
                    }
                }
            }
            __syncthreads();
            if (sel_flag) { t0 = 1; break; }
            prefix = (prefix << 8) | (unsigned int)sel_digit;
            kk = sel_kk;
            __syncthreads(); // protect sel_* from next pass's re-init
        }
        if (t0) { T = 0u; need = 0; }
        else    { T = prefix; need = kk; }
    }

    // ---- tie disambiguation ----
    // Common case: total eq-count == need -> all ==T kept -> keep = (kj >= T),
    // no ranking needed. Only on true fp32 duplicates at T (P ~ 4e-5/row) do
    // we run the stable-rank scan.
    int eqc = 0;
#pragma unroll
    for (int j = 0; j < 16; ++j) eqc += (key[j] == T) ? 1 : 0;
    int wsum = eqc;
#pragma unroll
    for (int d = 1; d < 64; d <<= 1) wsum += __shfl_down(wsum, d);
    if (lane == 0) wtot[wid] = wsum;
    __syncthreads(); // B3: tie totals ready
    const int tot = wtot[0] + wtot[1] + wtot[2] + wtot[3];

    float* __restrict__ orow = out + (size_t)row * ROW_LEN;

    if (tot == need) {
        // ---- emit fast path: no per-element rank bookkeeping ----
#pragma unroll
        for (int j = 0; j < 4; ++j) {
            f32x4 v;
#pragma unroll
            for (int c2 = 0; c2 < 4; ++c2) {
                const unsigned int kj = key[4 * j + c2];
                v[c2] = (kj >= T && T != 0u) ? __uint_as_float(kj) : 0.0f;
            }
            *(f32x4*)(orow + j * 1024 + tid * 4) = v;
        }
    } else {
        // ---- rare: ambiguous ties. Stable rank in column order ----
        // Column order == lexicographic (j, tid, c). Packed 4x16-bit scan.
        unsigned long long packed = 0ull;
#pragma unroll
        for (int j = 0; j < 4; ++j) {
            int e = 0;
#pragma unroll
            for (int c = 0; c < 4; ++c) e += (key[4 * j + c] == T) ? 1 : 0;
            packed |= (unsigned long long)e << (16 * j);
        }
        unsigned long long incp = packed;
#pragma unroll
        for (int d = 1; d < 64; d <<= 1) {
            unsigned long long v = __shfl_up(incp, d);
            if (lane >= d) incp += v;
        }
        if (lane == 63) wtot64[wid] = incp;
        __syncthreads(); // B4 (rare path only)
        unsigned long long b64 = 0ull;
        for (int w = 0; w < wid; ++w) b64 += wtot64[w];
        const unsigned long long exclp = b64 + incp - packed;
        const unsigned long long t64 = wtot64[0] + wtot64[1] + wtot64[2] + wtot64[3];
        int S[4];
        S[0] = 0;
        S[1] = (int)(t64 & 0xFFFFull);
        S[2] = S[1] + (int)((t64 >> 16) & 0xFFFFull);
        S[3] = S[2] + (int)((t64 >> 32) & 0xFFFFull);
#pragma unroll
        for (int j = 0; j < 4; ++j) {
            int rr = S[j] + (int)((exclp >> (16 * j)) & 0xFFFFull);
            f32x4 v;
#pragma unroll
            for (int c2 = 0; c2 < 4; ++c2) {
                const unsigned int kj = key[4 * j + c2];
                const bool eq = (kj == T);
                const bool keep = (kj > T) || (eq && rr < need);
                v[c2] = keep ? __uint_as_float(kj) : 0.0f;
                rr += eq ? 1 : 0;
            }
            *(f32x4*)(orow + j * 1024 + tid * 4) = v;
        }
    }
}

extern "C" void kernel_launch(void* const* d_in, const int* in_sizes, int n_in,
                              void* d_out, int out_size, void* d_ws, size_t ws_size,
                              hipStream_t stream)
{
    const float* x    = (const float*)d_in[0];
    const int*   kptr = (const int*)d_in[1];
    float*       out  = (float*)d_out;
    const int rows = in_sizes[0] / ROW_LEN;
    topk_relu_kernel<<<rows, TPB, 0, stream>>>(x, kptr, out, rows);
}